// Round 6
// baseline (162.634 us; speedup 1.0000x reference)
//
#include <hip/hip_runtime.h>
#include <math.h>
#include <float.h>

// Problem constants: B=4, S=2048, DIN=1024, DOUT=1024, E=16, K=2
#define DIN_  1024
#define DOUT_ 1024
#define NE    16
#define KK    2
#define NTOK  8192

// ws layout: [0,128KB)      : float wc[E][K][DIN]  compact expert columns
//            [128KB,192KB)  : float gwT[E][DIN]    transposed gate weights

// ---------------------------------------------------------------------------
// Prep kernel: build wc (expert columns 0,1) and gwT (gate_w transposed).
// ---------------------------------------------------------------------------
__global__ __launch_bounds__(256) void prep_kernel(
    const float* __restrict__ ew,   // [E, DIN, DOUT]
    const float* __restrict__ gw,   // [DIN, E]
    float* __restrict__ wc,         // [E, K, DIN]
    float* __restrict__ gwT)        // [E, DIN]
{
    int i = blockIdx.x * 256 + threadIdx.x;
    if (i < NE * KK * DIN_) {
        int d = i & (DIN_ - 1);
        int j = (i >> 10) & 1;
        int e = i >> 11;
        wc[i] = ew[(size_t)e * DIN_ * DOUT_ + (size_t)d * DOUT_ + j];
    } else if (i < NE * KK * DIN_ + NE * DIN_) {
        int k = i - NE * KK * DIN_;
        int d = k & (DIN_ - 1);
        int e = k >> 10;
        gwT[k] = gw[(size_t)d * NE + e];
    }
}

// ---------------------------------------------------------------------------
// Wave-autonomous fused kernel: one wave = 4 tokens, NO barriers, NO LDS.
// gate_w is read transposed (gwT) so every load is fully coalesced and
// each load feeds 16 independent FMAs (4 tokens x float4).
// ---------------------------------------------------------------------------
__global__ __launch_bounds__(256, 2) void moe_wave_kernel(
    const float* __restrict__ x,        // [NTOK, DIN]
    const float* __restrict__ gwT,      // [E, DIN]
    const float* __restrict__ gate_b,   // [E]
    const float* __restrict__ ebias,    // [E]
    const float* __restrict__ wc,       // [E, K, DIN]
    const float* __restrict__ expert_b, // [E, DOUT]
    float* __restrict__ out_final,      // [NTOK, DOUT]
    float* __restrict__ out_probs,      // [NTOK, E]
    float* __restrict__ out_idx,        // [NTOK, K] as float
    int write_aux)
{
    const int lane = threadIdx.x & 63;
    const int wid  = threadIdx.x >> 6;                // 0..3
    const int tok0 = (blockIdx.x * 4 + wid) * 4;      // 4 tokens per wave

    // ---- x rows into registers (kept for both phases), fully coalesced ---
    // lane covers d4 = c*64 + lane  (d = c*256 + 4*lane .. +3)
    float4 xr[4][4];
#pragma unroll
    for (int t = 0; t < 4; t++) {
        const float4* xp = (const float4*)(x + (size_t)(tok0 + t) * DIN_);
#pragma unroll
        for (int c = 0; c < 4; c++) xr[t][c] = xp[c * 64 + lane];
    }

    // ---- gating: coalesced gwT loads, 16 fp4-dots per load ---------------
    const float4* gwT4 = (const float4*)gwT;          // [E][256]
    float acc[4][NE];
#pragma unroll
    for (int t = 0; t < 4; t++)
#pragma unroll
        for (int e = 0; e < NE; e++) acc[t][e] = 0.f;

#pragma unroll
    for (int e = 0; e < NE; e++) {
        float4 g[4];
#pragma unroll
        for (int c = 0; c < 4; c++) g[c] = gwT4[e * 256 + c * 64 + lane];
#pragma unroll
        for (int t = 0; t < 4; t++) {
#pragma unroll
            for (int c = 0; c < 4; c++) {
                acc[t][e] += xr[t][c].x * g[c].x + xr[t][c].y * g[c].y
                           + xr[t][c].z * g[c].z + xr[t][c].w * g[c].w;
            }
        }
    }

    // ---- 64-lane butterfly: every lane gets full totals ------------------
#pragma unroll
    for (int e = 0; e < NE; e++) {
        float gb = gate_b[e];
#pragma unroll
        for (int t = 0; t < 4; t++) {
            float v = acc[t][e];
#pragma unroll
            for (int m = 32; m >= 1; m >>= 1) v += __shfl_xor(v, m, 64);
            acc[t][e] = v + gb;       // gate_output (pre-sigmoid)
        }
    }

    float eb[NE];
#pragma unroll
    for (int e = 0; e < NE; e++) eb[e] = ebias[e];

    // ---- top-2 per token, redundantly on every lane (static indices) -----
    int   i0[4], i1[4];
    float w0[4], w1[4];
#pragma unroll
    for (int t = 0; t < 4; t++) {
        int b0 = 0;
        float best = acc[t][0] + eb[0], bgo = acc[t][0];
#pragma unroll
        for (int e = 1; e < NE; e++) {
            float lg = acc[t][e] + eb[e];
            if (lg > best) { best = lg; bgo = acc[t][e]; b0 = e; }
        }
        int b1 = 0;
        float best2 = -FLT_MAX, bgo2 = 0.f;
#pragma unroll
        for (int e = 0; e < NE; e++) {
            float lg = acc[t][e] + eb[e];
            bool c = (e != b0) && (lg > best2);
            if (c) { best2 = lg; bgo2 = acc[t][e]; b1 = e; }
        }
        float p0 = 1.f / (1.f + expf(-bgo));
        float p1 = 1.f / (1.f + expf(-bgo2));
        float inv = 1.f / (p0 + p1);
        i0[t] = b0; i1[t] = b1;
        w0[t] = p0 * inv; w1[t] = p1 * inv;
    }

    // ---- aux outputs ------------------------------------------------------
    if (write_aux) {
        // probs: lane -> (t = lane>>4, e = lane&15); 64 contiguous floats
        int tsel = lane >> 4;
        int esel = lane & 15;
        float sg = 0.f;
#pragma unroll
        for (int t = 0; t < 4; t++)
#pragma unroll
            for (int e = 0; e < NE; e++) {
                bool m = (tsel == t) && (esel == e);
                sg = m ? acc[t][e] : sg;
            }
        out_probs[(size_t)tok0 * NE + lane] = 1.f / (1.f + expf(-sg));
        if (lane < 4) {
            out_idx[(size_t)(tok0 + lane) * KK + 0] = (float)i0[lane];
            out_idx[(size_t)(tok0 + lane) * KK + 1] = (float)i1[lane];
        }
    }

    // ---- expert dots: reuse x registers, wc coalesced (L2-hot) -----------
    float d0[4], d1[4];
#pragma unroll
    for (int t = 0; t < 4; t++) {
        const float4* wa = (const float4*)(wc + ((size_t)i0[t] * KK + 0) * DIN_);
        const float4* wb = (const float4*)(wc + ((size_t)i1[t] * KK + 1) * DIN_);
        float s0 = 0.f, s1 = 0.f;
#pragma unroll
        for (int c = 0; c < 4; c++) {
            float4 p = wa[c * 64 + lane];
            float4 q = wb[c * 64 + lane];
            s0 += xr[t][c].x * p.x + xr[t][c].y * p.y + xr[t][c].z * p.z + xr[t][c].w * p.w;
            s1 += xr[t][c].x * q.x + xr[t][c].y * q.y + xr[t][c].z * q.z + xr[t][c].w * q.w;
        }
        d0[t] = s0; d1[t] = s1;
    }
#pragma unroll
    for (int m = 32; m >= 1; m >>= 1) {
#pragma unroll
        for (int t = 0; t < 4; t++) {
            d0[t] += __shfl_xor(d0[t], m, 64);
            d1[t] += __shfl_xor(d1[t], m, 64);
        }
    }

    // ---- finalize + broadcast stores, fully coalesced --------------------
#pragma unroll
    for (int t = 0; t < 4; t++) {
        float f = w0[t] * (d0[t] + expert_b[(size_t)i0[t] * DOUT_ + 0])
                + w1[t] * (d1[t] + expert_b[(size_t)i1[t] * DOUT_ + 1]);
        float4 fv = make_float4(f, f, f, f);
        float4* o = (float4*)(out_final + (size_t)(tok0 + t) * DOUT_);
#pragma unroll
        for (int c = 0; c < 4; c++) o[c * 64 + lane] = fv;
    }
}

// ---------------------------------------------------------------------------
extern "C" void kernel_launch(void* const* d_in, const int* in_sizes, int n_in,
                              void* d_out, int out_size, void* d_ws, size_t ws_size,
                              hipStream_t stream) {
    const float* x        = (const float*)d_in[0];
    const float* gate_w   = (const float*)d_in[1];
    const float* gate_b   = (const float*)d_in[2];
    const float* expert_w = (const float*)d_in[3];
    const float* expert_b = (const float*)d_in[4];
    const float* ebias    = (const float*)d_in[5];
    float* out = (float*)d_out;

    float* wc  = (float*)d_ws;                          // 128 KB
    float* gwT = (float*)d_ws + (size_t)NE * KK * DIN_; // 64 KB

    float* out_final = out;
    float* out_probs = out + (size_t)NTOK * DOUT_;
    float* out_idx   = out_probs + (size_t)NTOK * NE;
    int write_aux = (out_size >= NTOK * DOUT_ + NTOK * NE + NTOK * KK) ? 1 : 0;

    int prep_n = NE * KK * DIN_ + NE * DIN_;            // 49152
    prep_kernel<<<(prep_n + 255) / 256, 256, 0, stream>>>(expert_w, gate_w, wc, gwT);
    // 16 tokens per block (4 per wave) -> 512 blocks
    moe_wave_kernel<<<NTOK / 16, 256, 0, stream>>>(
        x, gwT, gate_b, ebias, wc, expert_b,
        out_final, out_probs, out_idx, write_aux);
}